// Round 14
// baseline (294.055 us; speedup 1.0000x reference)
//
#include <hip/hip_runtime.h>
#include <hip/hip_fp16.h>

#define NN 100000
#define NE 1600000
#define SH 7
#define NB_BKT 782        // ceil(100000/128)
#define BCAP 3072         // edges per bucket cap (mean 2048, sigma~45: >20 sigma)
#define CSRCAP 3200       // BCAP + 128 self-edges
#define CHUNK 8192
#define TILES_TOTAL 3125  // 100000 / 32 exactly
#define PIPE_BLOCKS 512   // 2 blocks/CU

static inline int cdiv(long long a, int b) { return (int)((a + b - 1) / b); }

// fp16 quad load: base = float2 view of half array; idx in float2 units (4 halfs)
__device__ inline float4 ld_h4(const float2* __restrict__ base, size_t idx) {
    float2 v = base[idx];
    const __half2* p = (const __half2*)&v;
    float2 f0 = __half22float2(p[0]);
    float2 f1 = __half22float2(p[1]);
    return make_float4(f0.x, f0.y, f1.x, f1.y);
}

// fp16 row-slice FMA: v = 8 halfs (cols 8l..8l+7); acc0 = cols +0..3, acc1 = +4..7
__device__ inline void fma_h8(const float4& v, float w, float4& a0, float4& a1) {
    const __half2* hh = (const __half2*)&v;
    float2 f0 = __half22float2(hh[0]);
    float2 f1 = __half22float2(hh[1]);
    float2 f2 = __half22float2(hh[2]);
    float2 f3 = __half22float2(hh[3]);
    a0.x = fmaf(w, f0.x, a0.x); a0.y = fmaf(w, f0.y, a0.y);
    a0.z = fmaf(w, f1.x, a0.z); a0.w = fmaf(w, f1.y, a0.w);
    a1.x = fmaf(w, f2.x, a1.x); a1.y = fmaf(w, f2.y, a1.y);
    a1.z = fmaf(w, f3.x, a1.z); a1.w = fmaf(w, f3.y, a1.w);
}

// ======================= bucketed CSR build (fixed-cap, no hist/scan) ====
// packed u32: (r << 7) | (c & 127)
__global__ void partition_kernel(const int* __restrict__ row, const int* __restrict__ col,
                                 int* __restrict__ bcur,
                                 unsigned int* __restrict__ packed, int E) {
    __shared__ int lh[NB_BKT];
    __shared__ int lbase[NB_BKT];
    for (int i = threadIdx.x; i < NB_BKT; i += 256) lh[i] = 0;
    __syncthreads();
    int base = blockIdx.x * CHUNK;
    int end = min(base + CHUNK, E);
    for (int e = base + threadIdx.x; e < end; e += 256) atomicAdd(&lh[col[e] >> SH], 1);
    __syncthreads();
    for (int i = threadIdx.x; i < NB_BKT; i += 256) {
        int v = lh[i];
        lbase[i] = v ? atomicAdd(&bcur[i], v) : 0;
        lh[i] = 0;
    }
    __syncthreads();
    for (int e = base + threadIdx.x; e < end; e += 256) {
        int c = col[e];
        int r = row[e];
        int b = c >> SH;
        int off = atomicAdd(&lh[b], 1);
        packed[lbase[b] + off] = ((unsigned)r << 7) | (unsigned)(c & 127);
    }
}

// Per-bucket: degree count -> scan -> rowptr/rowend/self/dinv -> placement.
__global__ void bucket_nodes_place(const unsigned int* __restrict__ packed,
                                   const int* __restrict__ bcur, int* __restrict__ rowptr,
                                   int* __restrict__ rowend, float* __restrict__ dinv,
                                   int* __restrict__ csr_row, int N) {
    int b = blockIdx.x;
    __shared__ int lcnt[128];
    __shared__ int lcur[128];
    __shared__ int wt4[4];
    int t = threadIdx.x;
    if (t < 128) lcnt[t] = 0;
    __syncthreads();
    int s = b * BCAP;
    int e = bcur[b];                 // s + edges_in_bucket
    for (int i = s + t; i < e; i += 256)
        atomicAdd(&lcnt[packed[i] & 127u], 1);
    __syncthreads();
    int node = (b << SH) + t;
    int v = (t < 128 && node < N) ? lcnt[t] + 1 : 0;   // +1 = self-edge slot
    int lane = t & 63, w = t >> 6;
    int incl = v;
#pragma unroll
    for (int off = 1; off < 64; off <<= 1) {
        int u = __shfl_up(incl, off, 64);
        if (lane >= off) incl += u;
    }
    if (lane == 63) wt4[w] = incl;
    __syncthreads();
    int woff = 0;
    for (int i = 0; i < w; i++) woff += wt4[i];
    int excl = woff + incl - v;
    if (t < 128 && node < N) {
        int start = b * CSRCAP + excl;
        rowptr[node] = start;
        rowend[node] = start + v;
        csr_row[start] = node;       // self edge first in segment
        dinv[node] = rsqrtf((float)v);
        lcur[t] = start + 1;
    }
    __syncthreads();
    for (int i = s + t; i < e; i += 256) {   // packed range is L2-warm
        unsigned p = packed[i];
        int r = (int)(p >> 7);
        int pos = atomicAdd(&lcur[p & 127u], 1);
        csr_row[pos] = r;
    }
}

// ======================= y1 = x @ W1 (fp16 out) + bcur init ==============
// r28: GCN aggregation is linear -> gather(x)W1 == gather(xW1). Precompute
// y1 = xW1 and make L1 a pure fp16 gather over 64B rows.
__global__ void xw1_kernel(const float* __restrict__ x, const float* __restrict__ W1,
                           __half* __restrict__ y, int* __restrict__ bcur, int N) {
    __shared__ float xsm[64 * 21];
    __shared__ float Wsm[21 * 32];
    const int t = threadIdx.x;    // 256
    const int n0 = blockIdx.x * 64;
    if (blockIdx.x == 0)
        for (int i = t; i < NB_BKT; i += 256) bcur[i] = i * BCAP;
    for (int i = t; i < 21 * 32; i += 256) Wsm[i] = W1[i];
    const int nv = min(64, N - n0);
    for (int i = t; i < nv * 21; i += 256) xsm[i] = x[(size_t)n0 * 21 + i];
    __syncthreads();
    const int ng = t >> 2, jq = t & 3;    // 64 nodes x 4 col-quads (8 cols)
    const int node = n0 + ng;
    if (node >= N) return;
    float r[8];
#pragma unroll
    for (int j = 0; j < 8; j++) r[j] = 0.f;
    for (int k = 0; k < 21; k++) {
        float xv = xsm[ng * 21 + k];
#pragma unroll
        for (int j = 0; j < 8; j++)
            r[j] = fmaf(xv, Wsm[k * 32 + jq * 8 + j], r[j]);
    }
    float4 pk;
    __half2* ph = (__half2*)&pk;
    ph[0] = __float22half2_rn(make_float2(r[0], r[1]));
    ph[1] = __float22half2_rn(make_float2(r[2], r[3]));
    ph[2] = __float22half2_rn(make_float2(r[4], r[5]));
    ph[3] = __float22half2_rn(make_float2(r[6], r[7]));
    *(float4*)(y + (size_t)node * 32 + jq * 8) = pk;
}

// ======================= fused gather + GEMM (L2) ========================
// HALF_OUT: store output fp16 (RJ=8 -> 16B store).
// HALF_IN: gather input is fp16 rows of FIN halfs; lane loads float2.
template <int LPN, int FIN, int FOUT, int RJ, int OSTRIDE, bool HALF_OUT, bool HALF_IN>
__global__ __launch_bounds__(512) void gather_gemm(
    const float4* __restrict__ h, const int* __restrict__ rowptr,
    const int* __restrict__ rowend, const int* __restrict__ csr_row,
    const float* __restrict__ dinv, const float* __restrict__ W,
    const float* __restrict__ b, float* __restrict__ out, int N) {
    constexpr int NT = 512 / LPN;        // nodes per block
    constexpr int FINP = 4 * LPN;        // gathered row width (>= FIN)
    constexpr int XLD = FINP + 1;
    constexpr int JG = FOUT / RJ;        // must satisfy 512/JG == NT
    __shared__ float xs[NT * XLD];
    __shared__ float Ws[FIN * FOUT];
    __shared__ float bs[FOUT];
    const int t = threadIdx.x;
    const float2* hf2 = (const float2*)h;   // HALF_IN view

    for (int i = t; i < FIN * FOUT; i += 512) Ws[i] = W[i];
    if (t < FOUT) bs[t] = b[t];

    // ---- gather phase ----
    const int l = t % LPN;
    const int ny = t / LPN;
    const int node = blockIdx.x * NT + ny;
    float4 acc = make_float4(0.f, 0.f, 0.f, 0.f);
    if (node < N) {
        int s = rowptr[node], e = rowend[node];
        float dn = dinv[node];
        int i = s;
        for (; i + 3 < e; i += 4) {
            int r0 = csr_row[i], r1 = csr_row[i + 1], r2 = csr_row[i + 2], r3 = csr_row[i + 3];
            float w0 = dinv[r0] * dn, w1 = dinv[r1] * dn, w2 = dinv[r2] * dn, w3 = dinv[r3] * dn;
            float4 a0, a1, a2, a3;
            if constexpr (HALF_IN) {
                a0 = ld_h4(hf2, (size_t)r0 * LPN + l);
                a1 = ld_h4(hf2, (size_t)r1 * LPN + l);
                a2 = ld_h4(hf2, (size_t)r2 * LPN + l);
                a3 = ld_h4(hf2, (size_t)r3 * LPN + l);
            } else {
                a0 = h[(size_t)r0 * LPN + l];
                a1 = h[(size_t)r1 * LPN + l];
                a2 = h[(size_t)r2 * LPN + l];
                a3 = h[(size_t)r3 * LPN + l];
            }
            acc.x = fmaf(w0, a0.x, acc.x); acc.y = fmaf(w0, a0.y, acc.y);
            acc.z = fmaf(w0, a0.z, acc.z); acc.w = fmaf(w0, a0.w, acc.w);
            acc.x = fmaf(w1, a1.x, acc.x); acc.y = fmaf(w1, a1.y, acc.y);
            acc.z = fmaf(w1, a1.z, acc.z); acc.w = fmaf(w1, a1.w, acc.w);
            acc.x = fmaf(w2, a2.x, acc.x); acc.y = fmaf(w2, a2.y, acc.y);
            acc.z = fmaf(w2, a2.z, acc.z); acc.w = fmaf(w2, a2.w, acc.w);
            acc.x = fmaf(w3, a3.x, acc.x); acc.y = fmaf(w3, a3.y, acc.y);
            acc.z = fmaf(w3, a3.z, acc.z); acc.w = fmaf(w3, a3.w, acc.w);
        }
        for (; i < e; i++) {
            int r0 = csr_row[i];
            float w0 = dinv[r0] * dn;
            float4 a0;
            if constexpr (HALF_IN) a0 = ld_h4(hf2, (size_t)r0 * LPN + l);
            else                   a0 = h[(size_t)r0 * LPN + l];
            acc.x = fmaf(w0, a0.x, acc.x); acc.y = fmaf(w0, a0.y, acc.y);
            acc.z = fmaf(w0, a0.z, acc.z); acc.w = fmaf(w0, a0.w, acc.w);
        }
    }
    xs[ny * XLD + 4 * l + 0] = acc.x;
    xs[ny * XLD + 4 * l + 1] = acc.y;
    xs[ny * XLD + 4 * l + 2] = acc.z;
    xs[ny * XLD + 4 * l + 3] = acc.w;
    __syncthreads();

    // ---- GEMM phase ----
    const int jg = t % JG;
    const int ng = t / JG;
    float r[RJ];
#pragma unroll
    for (int jj = 0; jj < RJ; jj++) r[jj] = 0.f;
#pragma unroll 4
    for (int k = 0; k < FIN; k++) {
        float xv = xs[ng * XLD + k];
#pragma unroll
        for (int jj = 0; jj < RJ; jj++)
            r[jj] = fmaf(xv, Ws[k * FOUT + jg * RJ + jj], r[jj]);
    }
    int onode = blockIdx.x * NT + ng;
    if (onode < N) {
#pragma unroll
        for (int jj = 0; jj < RJ; jj++) r[jj] = fmaxf(r[jj] + bs[jg * RJ + jj], 0.f);
        if constexpr (HALF_OUT) {
            static_assert(!HALF_OUT || RJ == 8, "half path needs RJ==8");
            float4 pk;
            __half2* ph = (__half2*)&pk;
            ph[0] = __float22half2_rn(make_float2(r[0], r[1]));
            ph[1] = __float22half2_rn(make_float2(r[2], r[3]));
            ph[2] = __float22half2_rn(make_float2(r[4], r[5]));
            ph[3] = __float22half2_rn(make_float2(r[6], r[7]));
            *(float4*)((__half*)out + (size_t)onode * FOUT + jg * RJ) = pk;
        } else {
            float* orow = out + (size_t)onode * OSTRIDE + jg * RJ;
#pragma unroll
            for (int c = 0; c < RJ / 4; c++)
                *(float4*)&orow[4 * c] = make_float4(r[4 * c], r[4 * c + 1], r[4 * c + 2], r[4 * c + 3]);
        }
    }
}

// ================== standalone fp16 gather, 16B/lane (r29) ===============
// Rows = 32 halfs (64B); 4 lanes/node x float4 (8 halfs). Unroll-6 => 6
// lines in flight/lane (vs 4 at the old 8B/lane shape) and half the load
// instructions. Per-edge accumulation order identical to r28 (sequential
// in i) -> absmax unchanged.
// HRELU: out fp16 relu(acc+bias), 16B/lane. else: out f32 cols 8l..8l+7
// with <21 guard (+bias).
template <bool HRELU>
__global__ void gather4_h16(const float4* __restrict__ h, const int* __restrict__ rowptr,
                            const int* __restrict__ rowend, const int* __restrict__ csr_row,
                            const float* __restrict__ dinv, const float* __restrict__ bias,
                            float* __restrict__ outp, int N) {
    int node = blockIdx.x * blockDim.y + threadIdx.y;
    if (node >= N) return;
    int l = threadIdx.x;              // 0..3
    int s = rowptr[node], e = rowend[node];
    float dn = dinv[node];
    float4 acc0 = make_float4(0.f, 0.f, 0.f, 0.f);
    float4 acc1 = make_float4(0.f, 0.f, 0.f, 0.f);
    int i = s;
    for (; i + 5 < e; i += 6) {
        int r0 = csr_row[i],     r1 = csr_row[i + 1], r2 = csr_row[i + 2];
        int r3 = csr_row[i + 3], r4 = csr_row[i + 4], r5 = csr_row[i + 5];
        float w0 = dinv[r0] * dn, w1 = dinv[r1] * dn, w2 = dinv[r2] * dn;
        float w3 = dinv[r3] * dn, w4 = dinv[r4] * dn, w5 = dinv[r5] * dn;
        float4 v0 = h[(size_t)r0 * 4 + l];
        float4 v1 = h[(size_t)r1 * 4 + l];
        float4 v2 = h[(size_t)r2 * 4 + l];
        float4 v3 = h[(size_t)r3 * 4 + l];
        float4 v4 = h[(size_t)r4 * 4 + l];
        float4 v5 = h[(size_t)r5 * 4 + l];
        fma_h8(v0, w0, acc0, acc1);
        fma_h8(v1, w1, acc0, acc1);
        fma_h8(v2, w2, acc0, acc1);
        fma_h8(v3, w3, acc0, acc1);
        fma_h8(v4, w4, acc0, acc1);
        fma_h8(v5, w5, acc0, acc1);
    }
    for (; i < e; i++) {
        int r0 = csr_row[i];
        float w0 = dinv[r0] * dn;
        float4 v0 = h[(size_t)r0 * 4 + l];
        fma_h8(v0, w0, acc0, acc1);
    }
    int j = 8 * l;
    float v[8] = {acc0.x, acc0.y, acc0.z, acc0.w, acc1.x, acc1.y, acc1.z, acc1.w};
    if constexpr (HRELU) {
        float4 pk;
        __half2* ph = (__half2*)&pk;
#pragma unroll
        for (int c = 0; c < 4; c++) {
            float a = fmaxf(v[2 * c] + bias[j + 2 * c], 0.f);
            float b2 = fmaxf(v[2 * c + 1] + bias[j + 2 * c + 1], 0.f);
            ph[c] = __float22half2_rn(make_float2(a, b2));
        }
        *(float4*)((__half*)outp + (size_t)node * 32 + j) = pk;
    } else {
#pragma unroll
        for (int c = 0; c < 8; c++) {
            int jj = j + c;
            if (jj < 21) outp[(size_t)node * 21 + jj] = v[c] + bias[jj];
        }
    }
}

// ============ pipelined fused L3 gather + L3/L4 GEMM (r27, unchanged) ====
// r19 4P/4C 32-frame (proven local optimum); fp16 h2 in, fp16 h4 out.
__global__ __launch_bounds__(512, 4) void gather_gemm_l3l4_pipe(
    const float4* __restrict__ h, const int* __restrict__ rowptr,
    const int* __restrict__ rowend, const int* __restrict__ csr_row,
    const float* __restrict__ dinv, const float* __restrict__ W3,
    const float* __restrict__ b3, const float* __restrict__ W4,
    float* __restrict__ out, int N) {
    __shared__ float xs[2][32 * 65];
    __shared__ float4 W3v[64 * 32];
    __shared__ float4 W4v[16 * 48];
    __shared__ float b3s[128];
    const int t = threadIdx.x;
    const int b = blockIdx.x;

    // ---- weight staging (r19 original) ----
    for (int sid = t; sid < 64 * 32; sid += 512) {
        int k = sid >> 5, q = sid & 31;
        int jg = q >> 2, c = q & 3;
        W3v[(k << 5) + (c << 3) + jg] = ((const float4*)W3)[sid];
    }
    for (int cid = t; cid < 16 * 48; cid += 512) {
        int i = cid / 48, rem = cid - i * 48;
        int jq = rem >> 3, jg = rem & 7;
        int k = jg * 16 + i;
        float v0 = (4 * jq + 0 < 21) ? W4[k * 21 + 4 * jq + 0] : 0.f;
        float v1 = (4 * jq + 1 < 21) ? W4[k * 21 + 4 * jq + 1] : 0.f;
        float v2 = (4 * jq + 2 < 21) ? W4[k * 21 + 4 * jq + 2] : 0.f;
        float v3 = (4 * jq + 3 < 21) ? W4[k * 21 + 4 * jq + 3] : 0.f;
        W4v[cid] = make_float4(v0, v1, v2, v3);
    }
    if (t < 128) b3s[t] = b3[t];
    __syncthreads();

    // number of tiles this block owns (static assignment, r19)
    const int R = (TILES_TOTAL - b + PIPE_BLOCKS - 1) / PIPE_BLOCKS;

    for (int r = 0; r <= R; r++) {
        if (t < 256) {
            // ---- producer: gather tile r into xs[r&1] (fp16 h2) ----
            if (r < R) {
                const int l = t & 7;
                const int ny = t >> 3;
                const int node = (b + PIPE_BLOCKS * r) * 32 + ny;
                float4 acc0 = make_float4(0.f, 0.f, 0.f, 0.f);
                float4 acc1 = make_float4(0.f, 0.f, 0.f, 0.f);
                if (node < N) {
                    int s = rowptr[node], e = rowend[node];
                    float dn = dinv[node];
                    int i = s;
                    for (; i + 5 < e; i += 6) {
                        int r0 = csr_row[i],     r1 = csr_row[i + 1], r2 = csr_row[i + 2];
                        int r3 = csr_row[i + 3], r4 = csr_row[i + 4], r5 = csr_row[i + 5];
                        float w0 = dinv[r0] * dn, w1 = dinv[r1] * dn, w2 = dinv[r2] * dn;
                        float w3 = dinv[r3] * dn, w4 = dinv[r4] * dn, w5 = dinv[r5] * dn;
                        float4 v0 = h[(size_t)r0 * 8 + l];
                        float4 v1 = h[(size_t)r1 * 8 + l];
                        float4 v2 = h[(size_t)r2 * 8 + l];
                        float4 v3 = h[(size_t)r3 * 8 + l];
                        float4 v4 = h[(size_t)r4 * 8 + l];
                        float4 v5 = h[(size_t)r5 * 8 + l];
                        fma_h8(v0, w0, acc0, acc1);
                        fma_h8(v1, w1, acc0, acc1);
                        fma_h8(v2, w2, acc0, acc1);
                        fma_h8(v3, w3, acc0, acc1);
                        fma_h8(v4, w4, acc0, acc1);
                        fma_h8(v5, w5, acc0, acc1);
                    }
                    for (; i < e; i++) {
                        int r0 = csr_row[i];
                        float w0 = dinv[r0] * dn;
                        float4 v0 = h[(size_t)r0 * 8 + l];
                        fma_h8(v0, w0, acc0, acc1);
                    }
                }
                float* xr = xs[r & 1] + ny * 65 + 8 * l;
                xr[0] = acc0.x; xr[1] = acc0.y; xr[2] = acc0.z; xr[3] = acc0.w;
                xr[4] = acc1.x; xr[5] = acc1.y; xr[6] = acc1.z; xr[7] = acc1.w;
            }
        } else {
            // ---- consumer: GEMM tile r-1 from xs[(r-1)&1] (r25 structure) ----
            if (r >= 1) {
                const int jg = t & 7;
                const int ng = (t >> 3) & 31;
                const int node = (b + PIPE_BLOCKS * (r - 1)) * 32 + ng;
                const float* arow = xs[(r - 1) & 1] + ng * 65;

                float accA[16];
#pragma unroll
                for (int jj = 0; jj < 16; jj++) accA[jj] = 0.f;
#pragma unroll 4
                for (int k = 0; k < 64; k++) {
                    float xa = arow[k];
                    const float4* wb = &W3v[(k << 5) + jg];
#pragma unroll
                    for (int c = 0; c < 4; c++) {
                        float4 w = wb[c << 3];
                        accA[4 * c + 0] = fmaf(xa, w.x, accA[4 * c + 0]);
                        accA[4 * c + 1] = fmaf(xa, w.y, accA[4 * c + 1]);
                        accA[4 * c + 2] = fmaf(xa, w.z, accA[4 * c + 2]);
                        accA[4 * c + 3] = fmaf(xa, w.w, accA[4 * c + 3]);
                    }
                }
#pragma unroll
                for (int jj = 0; jj < 16; jj++) {
                    float bb = b3s[jg * 16 + jj];
                    accA[jj] = fmaxf(accA[jj] + bb, 0.f);
                }

                float pA[24];
#pragma unroll
                for (int j = 0; j < 24; j++) pA[j] = 0.f;
#pragma unroll
                for (int i = 0; i < 16; i++) {
                    float ha = accA[i];
                    const float4* wb = &W4v[i * 48 + jg];
#pragma unroll
                    for (int jq = 0; jq < 6; jq++) {
                        float4 w = wb[jq << 3];
                        pA[4 * jq + 0] = fmaf(ha, w.x, pA[4 * jq + 0]);
                        pA[4 * jq + 1] = fmaf(ha, w.y, pA[4 * jq + 1]);
                        pA[4 * jq + 2] = fmaf(ha, w.z, pA[4 * jq + 2]);
                        pA[4 * jq + 3] = fmaf(ha, w.w, pA[4 * jq + 3]);
                    }
                }
#pragma unroll
                for (int m = 1; m < 8; m <<= 1) {
#pragma unroll
                    for (int j = 0; j < 24; j++)
                        pA[j] += __shfl_xor(pA[j], m, 8);
                }
                if (node < N) {
                    __half* orow = (__half*)out + (size_t)node * 32;
                    float2 pk = make_float2(0.f, 0.f);   // 4 zero halfs
                    if (jg < 6) {
                        __half2* ph = (__half2*)&pk;
                        ph[0] = __float22half2_rn(make_float2(pA[4 * jg + 0], pA[4 * jg + 1]));
                        ph[1] = __float22half2_rn(make_float2(pA[4 * jg + 2], pA[4 * jg + 3]));
                    }
                    *(float2*)(orow + 4 * jg) = pk;
                }
            }
        }
        __syncthreads();
    }
}

// ======================= launch ==========================================
extern "C" void kernel_launch(void* const* d_in, const int* in_sizes, int n_in,
                              void* d_out, int out_size, void* d_ws, size_t ws_size,
                              hipStream_t stream) {
    const float* x  = (const float*)d_in[0];
    const int*   ei = (const int*)d_in[1];
    const float* W1 = (const float*)d_in[2]; const float* b1 = (const float*)d_in[3];
    const float* W2 = (const float*)d_in[4]; const float* b2 = (const float*)d_in[5];
    const float* W3 = (const float*)d_in[6]; const float* b3 = (const float*)d_in[7];
    const float* W4 = (const float*)d_in[8]; const float* b4 = (const float*)d_in[9];
    const int* row = ei;
    const int* col = ei + NE;
    float* out = (float*)d_out;

    // workspace layout (floats)
    float* A      = (float*)d_ws;                  // region A: packed -> h1(fp16) -> h4(fp16)
    float* B      = A + (size_t)NN * 128;          // region B: y1(fp16) -> h2(fp16)
    float* dinv   = B + (size_t)NN * 128;          // N
    int*   rowptr = (int*)(dinv + NN);             // N
    int*   rowend = rowptr + NN;                   // N
    int*   csr_row= rowend + NN;                   // NB_BKT * CSRCAP = 2.5M
    int*   bcur   = csr_row + (size_t)NB_BKT * CSRCAP;   // NB_BKT
    // packed u32 (r<<7 | c&127), bucket-strided cap BCAP; aliases A (dead pre-L1)
    unsigned int* packed = (unsigned int*)A;       // NB_BKT * BCAP = 2.4M < N*128

    const int NCH = cdiv(NE, CHUNK);    // 196

    // ---- y1 = x @ W1 (fp16) + bcur init ----
    xw1_kernel<<<cdiv(NN, 64), 256, 0, stream>>>(x, W1, (__half*)B, bcur, NN);
    // ---- fixed-cap bucketed CSR build (2 dispatches) ----
    partition_kernel<<<NCH, 256, 0, stream>>>(row, col, bcur, packed, NE);
    bucket_nodes_place<<<NB_BKT, 256, 0, stream>>>(packed, bcur, rowptr, rowend, dinv, csr_row, NN);

    // ---- L1: gather(y1 fp16, 16B/lane) + b1 + relu : B -> A (h1 FP16) ----
    {
        dim3 blk(4, 64);
        gather4_h16<true><<<cdiv(NN, 64), blk, 0, stream>>>(
            (const float4*)B, rowptr, rowend, csr_row, dinv, b1, A, NN);
    }
    // ---- L2: gather(h1 fp16)+gemm 32->64 +b relu : A -> B (h2 FP16, 128B rows) ----
    gather_gemm<8, 32, 64, 8, 64, true, true><<<cdiv(NN, 64), 512, 0, stream>>>(
        (const float4*)A, rowptr, rowend, csr_row, dinv, W2, b2, B, NN);
    // ---- pipelined fused L3 gather(fp16 h2) + L3/L4 GEMM: B -> A (h4 FP16) ----
    gather_gemm_l3l4_pipe<<<PIPE_BLOCKS, 512, 0, stream>>>(
        (const float4*)B, rowptr, rowend, csr_row, dinv, W3, b3, W4, A, NN);
    // ---- L4: gather(h4 fp16, 16B/lane) + b4 : A -> out (f32, stride 21) ----
    {
        dim3 blk(4, 64);
        gather4_h16<false><<<cdiv(NN, 64), blk, 0, stream>>>(
            (const float4*)A, rowptr, rowend, csr_row, dinv, b4, out, NN);
    }
}

// Round 15
// 289.771 us; speedup vs baseline: 1.0148x; 1.0148x over previous
//
#include <hip/hip_runtime.h>
#include <hip/hip_fp16.h>

#define NN 100000
#define NE 1600000
#define SH 7
#define NB_BKT 782        // ceil(100000/128)
#define BCAP 3072         // edges per bucket cap (mean 2048, sigma~45: >20 sigma)
#define CSRCAP 3200       // BCAP + 128 self-edges
#define CHUNK 4096        // r30: 391 blocks (was 8192/196 -- under-occupied)
#define TILES_TOTAL 3125  // 100000 / 32 exactly
#define PIPE_BLOCKS 512   // 2 blocks/CU

static inline int cdiv(long long a, int b) { return (int)((a + b - 1) / b); }

// fp16 quad load: base = float2 view of half array; idx in float2 units (4 halfs)
__device__ inline float4 ld_h4(const float2* __restrict__ base, size_t idx) {
    float2 v = base[idx];
    const __half2* p = (const __half2*)&v;
    float2 f0 = __half22float2(p[0]);
    float2 f1 = __half22float2(p[1]);
    return make_float4(f0.x, f0.y, f1.x, f1.y);
}

// fp16 row-slice FMA: v = 8 halfs (cols 8l..8l+7); acc0 = cols +0..3, acc1 = +4..7
__device__ inline void fma_h8(const float4& v, float w, float4& a0, float4& a1) {
    const __half2* hh = (const __half2*)&v;
    float2 f0 = __half22float2(hh[0]);
    float2 f1 = __half22float2(hh[1]);
    float2 f2 = __half22float2(hh[2]);
    float2 f3 = __half22float2(hh[3]);
    a0.x = fmaf(w, f0.x, a0.x); a0.y = fmaf(w, f0.y, a0.y);
    a0.z = fmaf(w, f1.x, a0.z); a0.w = fmaf(w, f1.y, a0.w);
    a1.x = fmaf(w, f2.x, a1.x); a1.y = fmaf(w, f2.y, a1.y);
    a1.z = fmaf(w, f3.x, a1.z); a1.w = fmaf(w, f3.y, a1.w);
}

// ======================= bucketed CSR build (fixed-cap, no hist/scan) ====
// packed u32: (r << 7) | (c & 127)
__global__ void partition_kernel(const int* __restrict__ row, const int* __restrict__ col,
                                 int* __restrict__ bcur,
                                 unsigned int* __restrict__ packed, int E) {
    __shared__ int lh[NB_BKT];
    __shared__ int lbase[NB_BKT];
    for (int i = threadIdx.x; i < NB_BKT; i += 256) lh[i] = 0;
    __syncthreads();
    int base = blockIdx.x * CHUNK;
    int end = min(base + CHUNK, E);
    for (int e = base + threadIdx.x; e < end; e += 256) atomicAdd(&lh[col[e] >> SH], 1);
    __syncthreads();
    for (int i = threadIdx.x; i < NB_BKT; i += 256) {
        int v = lh[i];
        lbase[i] = v ? atomicAdd(&bcur[i], v) : 0;
        lh[i] = 0;
    }
    __syncthreads();
    for (int e = base + threadIdx.x; e < end; e += 256) {
        int c = col[e];
        int r = row[e];
        int b = c >> SH;
        int off = atomicAdd(&lh[b], 1);
        packed[lbase[b] + off] = ((unsigned)r << 7) | (unsigned)(c & 127);
    }
}

// Per-bucket: degree count -> scan -> rowptr/rowend/self/dinv -> placement.
__global__ void bucket_nodes_place(const unsigned int* __restrict__ packed,
                                   const int* __restrict__ bcur, int* __restrict__ rowptr,
                                   int* __restrict__ rowend, float* __restrict__ dinv,
                                   int* __restrict__ csr_row, int N) {
    int b = blockIdx.x;
    __shared__ int lcnt[128];
    __shared__ int lcur[128];
    __shared__ int wt4[4];
    int t = threadIdx.x;
    if (t < 128) lcnt[t] = 0;
    __syncthreads();
    int s = b * BCAP;
    int e = bcur[b];                 // s + edges_in_bucket
    for (int i = s + t; i < e; i += 256)
        atomicAdd(&lcnt[packed[i] & 127u], 1);
    __syncthreads();
    int node = (b << SH) + t;
    int v = (t < 128 && node < N) ? lcnt[t] + 1 : 0;   // +1 = self-edge slot
    int lane = t & 63, w = t >> 6;
    int incl = v;
#pragma unroll
    for (int off = 1; off < 64; off <<= 1) {
        int u = __shfl_up(incl, off, 64);
        if (lane >= off) incl += u;
    }
    if (lane == 63) wt4[w] = incl;
    __syncthreads();
    int woff = 0;
    for (int i = 0; i < w; i++) woff += wt4[i];
    int excl = woff + incl - v;
    if (t < 128 && node < N) {
        int start = b * CSRCAP + excl;
        rowptr[node] = start;
        rowend[node] = start + v;
        csr_row[start] = node;       // self edge first in segment
        dinv[node] = rsqrtf((float)v);
        lcur[t] = start + 1;
    }
    __syncthreads();
    for (int i = s + t; i < e; i += 256) {   // packed range is L2-warm
        unsigned p = packed[i];
        int r = (int)(p >> 7);
        int pos = atomicAdd(&lcur[p & 127u], 1);
        csr_row[pos] = r;
    }
}

// ======================= y1 = x @ W1 (fp16 out) + bcur init ==============
// r28: GCN aggregation is linear -> gather(x)W1 == gather(xW1). Precompute
// y1 = xW1 and make L1 a pure fp16 gather over 64B rows.
__global__ void xw1_kernel(const float* __restrict__ x, const float* __restrict__ W1,
                           __half* __restrict__ y, int* __restrict__ bcur, int N) {
    __shared__ float xsm[64 * 21];
    __shared__ float Wsm[21 * 32];
    const int t = threadIdx.x;    // 256
    const int n0 = blockIdx.x * 64;
    if (blockIdx.x == 0)
        for (int i = t; i < NB_BKT; i += 256) bcur[i] = i * BCAP;
    for (int i = t; i < 21 * 32; i += 256) Wsm[i] = W1[i];
    const int nv = min(64, N - n0);
    for (int i = t; i < nv * 21; i += 256) xsm[i] = x[(size_t)n0 * 21 + i];
    __syncthreads();
    const int ng = t >> 2, jq = t & 3;    // 64 nodes x 4 col-quads (8 cols)
    const int node = n0 + ng;
    if (node >= N) return;
    float r[8];
#pragma unroll
    for (int j = 0; j < 8; j++) r[j] = 0.f;
    for (int k = 0; k < 21; k++) {
        float xv = xsm[ng * 21 + k];
#pragma unroll
        for (int j = 0; j < 8; j++)
            r[j] = fmaf(xv, Wsm[k * 32 + jq * 8 + j], r[j]);
    }
    float4 pk;
    __half2* ph = (__half2*)&pk;
    ph[0] = __float22half2_rn(make_float2(r[0], r[1]));
    ph[1] = __float22half2_rn(make_float2(r[2], r[3]));
    ph[2] = __float22half2_rn(make_float2(r[4], r[5]));
    ph[3] = __float22half2_rn(make_float2(r[6], r[7]));
    *(float4*)(y + (size_t)node * 32 + jq * 8) = pk;
}

// ======================= fused gather + GEMM (L2) ========================
// HALF_OUT: store output fp16 (RJ=8 -> 16B store).
// HALF_IN: gather input is fp16 rows of FIN halfs; lane loads float2.
template <int LPN, int FIN, int FOUT, int RJ, int OSTRIDE, bool HALF_OUT, bool HALF_IN>
__global__ __launch_bounds__(512) void gather_gemm(
    const float4* __restrict__ h, const int* __restrict__ rowptr,
    const int* __restrict__ rowend, const int* __restrict__ csr_row,
    const float* __restrict__ dinv, const float* __restrict__ W,
    const float* __restrict__ b, float* __restrict__ out, int N) {
    constexpr int NT = 512 / LPN;        // nodes per block
    constexpr int FINP = 4 * LPN;        // gathered row width (>= FIN)
    constexpr int XLD = FINP + 1;
    constexpr int JG = FOUT / RJ;        // must satisfy 512/JG == NT
    __shared__ float xs[NT * XLD];
    __shared__ float Ws[FIN * FOUT];
    __shared__ float bs[FOUT];
    const int t = threadIdx.x;
    const float2* hf2 = (const float2*)h;   // HALF_IN view

    for (int i = t; i < FIN * FOUT; i += 512) Ws[i] = W[i];
    if (t < FOUT) bs[t] = b[t];

    // ---- gather phase ----
    const int l = t % LPN;
    const int ny = t / LPN;
    const int node = blockIdx.x * NT + ny;
    float4 acc = make_float4(0.f, 0.f, 0.f, 0.f);
    if (node < N) {
        int s = rowptr[node], e = rowend[node];
        float dn = dinv[node];
        int i = s;
        for (; i + 3 < e; i += 4) {
            int r0 = csr_row[i], r1 = csr_row[i + 1], r2 = csr_row[i + 2], r3 = csr_row[i + 3];
            float w0 = dinv[r0] * dn, w1 = dinv[r1] * dn, w2 = dinv[r2] * dn, w3 = dinv[r3] * dn;
            float4 a0, a1, a2, a3;
            if constexpr (HALF_IN) {
                a0 = ld_h4(hf2, (size_t)r0 * LPN + l);
                a1 = ld_h4(hf2, (size_t)r1 * LPN + l);
                a2 = ld_h4(hf2, (size_t)r2 * LPN + l);
                a3 = ld_h4(hf2, (size_t)r3 * LPN + l);
            } else {
                a0 = h[(size_t)r0 * LPN + l];
                a1 = h[(size_t)r1 * LPN + l];
                a2 = h[(size_t)r2 * LPN + l];
                a3 = h[(size_t)r3 * LPN + l];
            }
            acc.x = fmaf(w0, a0.x, acc.x); acc.y = fmaf(w0, a0.y, acc.y);
            acc.z = fmaf(w0, a0.z, acc.z); acc.w = fmaf(w0, a0.w, acc.w);
            acc.x = fmaf(w1, a1.x, acc.x); acc.y = fmaf(w1, a1.y, acc.y);
            acc.z = fmaf(w1, a1.z, acc.z); acc.w = fmaf(w1, a1.w, acc.w);
            acc.x = fmaf(w2, a2.x, acc.x); acc.y = fmaf(w2, a2.y, acc.y);
            acc.z = fmaf(w2, a2.z, acc.z); acc.w = fmaf(w2, a2.w, acc.w);
            acc.x = fmaf(w3, a3.x, acc.x); acc.y = fmaf(w3, a3.y, acc.y);
            acc.z = fmaf(w3, a3.z, acc.z); acc.w = fmaf(w3, a3.w, acc.w);
        }
        for (; i < e; i++) {
            int r0 = csr_row[i];
            float w0 = dinv[r0] * dn;
            float4 a0;
            if constexpr (HALF_IN) a0 = ld_h4(hf2, (size_t)r0 * LPN + l);
            else                   a0 = h[(size_t)r0 * LPN + l];
            acc.x = fmaf(w0, a0.x, acc.x); acc.y = fmaf(w0, a0.y, acc.y);
            acc.z = fmaf(w0, a0.z, acc.z); acc.w = fmaf(w0, a0.w, acc.w);
        }
    }
    xs[ny * XLD + 4 * l + 0] = acc.x;
    xs[ny * XLD + 4 * l + 1] = acc.y;
    xs[ny * XLD + 4 * l + 2] = acc.z;
    xs[ny * XLD + 4 * l + 3] = acc.w;
    __syncthreads();

    // ---- GEMM phase ----
    const int jg = t % JG;
    const int ng = t / JG;
    float r[RJ];
#pragma unroll
    for (int jj = 0; jj < RJ; jj++) r[jj] = 0.f;
#pragma unroll 4
    for (int k = 0; k < FIN; k++) {
        float xv = xs[ng * XLD + k];
#pragma unroll
        for (int jj = 0; jj < RJ; jj++)
            r[jj] = fmaf(xv, Ws[k * FOUT + jg * RJ + jj], r[jj]);
    }
    int onode = blockIdx.x * NT + ng;
    if (onode < N) {
#pragma unroll
        for (int jj = 0; jj < RJ; jj++) r[jj] = fmaxf(r[jj] + bs[jg * RJ + jj], 0.f);
        if constexpr (HALF_OUT) {
            static_assert(!HALF_OUT || RJ == 8, "half path needs RJ==8");
            float4 pk;
            __half2* ph = (__half2*)&pk;
            ph[0] = __float22half2_rn(make_float2(r[0], r[1]));
            ph[1] = __float22half2_rn(make_float2(r[2], r[3]));
            ph[2] = __float22half2_rn(make_float2(r[4], r[5]));
            ph[3] = __float22half2_rn(make_float2(r[6], r[7]));
            *(float4*)((__half*)out + (size_t)onode * FOUT + jg * RJ) = pk;
        } else {
            float* orow = out + (size_t)onode * OSTRIDE + jg * RJ;
#pragma unroll
            for (int c = 0; c < RJ / 4; c++)
                *(float4*)&orow[4 * c] = make_float4(r[4 * c], r[4 * c + 1], r[4 * c + 2], r[4 * c + 3]);
        }
    }
}

// ======================= standalone gather (r28 proven shape) ============
// HALF_IN: h rows are fp16 (4*LPN halfs); lane loads float2 (4 halfs).
// HRELU_OUT: out = fp16 relu(acc + bias), 4 halfs (8B) per lane.
template <int LPN, bool BIAS, bool STORE21, bool HALF_IN, bool HRELU_OUT>
__global__ void gather4_kernel(const float4* __restrict__ h, const int* __restrict__ rowptr,
                               const int* __restrict__ rowend, const int* __restrict__ csr_row,
                               const float* __restrict__ dinv, const float* __restrict__ bias,
                               float* __restrict__ outp, int N) {
    int node = blockIdx.x * blockDim.y + threadIdx.y;
    if (node >= N) return;
    int l = threadIdx.x;
    int s = rowptr[node], e = rowend[node];
    float dn = dinv[node];
    const float2* hf2 = (const float2*)h;
    float4 acc = make_float4(0.f, 0.f, 0.f, 0.f);
    int i = s;
    for (; i + 3 < e; i += 4) {
        int r0 = csr_row[i], r1 = csr_row[i + 1], r2 = csr_row[i + 2], r3 = csr_row[i + 3];
        float w0 = dinv[r0] * dn, w1 = dinv[r1] * dn, w2 = dinv[r2] * dn, w3 = dinv[r3] * dn;
        float4 a0, a1, a2, a3;
        if constexpr (HALF_IN) {
            a0 = ld_h4(hf2, (size_t)r0 * LPN + l);
            a1 = ld_h4(hf2, (size_t)r1 * LPN + l);
            a2 = ld_h4(hf2, (size_t)r2 * LPN + l);
            a3 = ld_h4(hf2, (size_t)r3 * LPN + l);
        } else {
            a0 = h[(size_t)r0 * LPN + l];
            a1 = h[(size_t)r1 * LPN + l];
            a2 = h[(size_t)r2 * LPN + l];
            a3 = h[(size_t)r3 * LPN + l];
        }
        acc.x = fmaf(w0, a0.x, acc.x); acc.y = fmaf(w0, a0.y, acc.y);
        acc.z = fmaf(w0, a0.z, acc.z); acc.w = fmaf(w0, a0.w, acc.w);
        acc.x = fmaf(w1, a1.x, acc.x); acc.y = fmaf(w1, a1.y, acc.y);
        acc.z = fmaf(w1, a1.z, acc.z); acc.w = fmaf(w1, a1.w, acc.w);
        acc.x = fmaf(w2, a2.x, acc.x); acc.y = fmaf(w2, a2.y, acc.y);
        acc.z = fmaf(w2, a2.z, acc.z); acc.w = fmaf(w2, a2.w, acc.w);
        acc.x = fmaf(w3, a3.x, acc.x); acc.y = fmaf(w3, a3.y, acc.y);
        acc.z = fmaf(w3, a3.z, acc.z); acc.w = fmaf(w3, a3.w, acc.w);
    }
    for (; i < e; i++) {
        int r0 = csr_row[i];
        float w0 = dinv[r0] * dn;
        float4 a0;
        if constexpr (HALF_IN) a0 = ld_h4(hf2, (size_t)r0 * LPN + l);
        else                   a0 = h[(size_t)r0 * LPN + l];
        acc.x = fmaf(w0, a0.x, acc.x); acc.y = fmaf(w0, a0.y, acc.y);
        acc.z = fmaf(w0, a0.z, acc.z); acc.w = fmaf(w0, a0.w, acc.w);
    }
    if constexpr (HRELU_OUT) {
        int j = 4 * l;
        float v0 = fmaxf(acc.x + bias[j + 0], 0.f);
        float v1 = fmaxf(acc.y + bias[j + 1], 0.f);
        float v2 = fmaxf(acc.z + bias[j + 2], 0.f);
        float v3 = fmaxf(acc.w + bias[j + 3], 0.f);
        float2 pk;
        __half2* ph = (__half2*)&pk;
        ph[0] = __float22half2_rn(make_float2(v0, v1));
        ph[1] = __float22half2_rn(make_float2(v2, v3));
        *(float2*)((__half*)outp + (size_t)node * (4 * LPN) + j) = pk;
    } else if (STORE21) {
        int j = 4 * l;
        float v[4] = {acc.x, acc.y, acc.z, acc.w};
#pragma unroll
        for (int c = 0; c < 4; c++) {
            int jj = j + c;
            if (jj < 21) outp[(size_t)node * 21 + jj] = v[c] + (BIAS ? bias[jj] : 0.f);
        }
    } else {
        ((float4*)outp)[(size_t)node * LPN + l] = acc;
    }
}

// ============ pipelined fused L3 gather + L3/L4 GEMM (r27, unchanged) ====
// r19 4P/4C 32-frame (proven local optimum); fp16 h2 in, fp16 h4 out.
__global__ __launch_bounds__(512, 4) void gather_gemm_l3l4_pipe(
    const float4* __restrict__ h, const int* __restrict__ rowptr,
    const int* __restrict__ rowend, const int* __restrict__ csr_row,
    const float* __restrict__ dinv, const float* __restrict__ W3,
    const float* __restrict__ b3, const float* __restrict__ W4,
    float* __restrict__ out, int N) {
    __shared__ float xs[2][32 * 65];
    __shared__ float4 W3v[64 * 32];
    __shared__ float4 W4v[16 * 48];
    __shared__ float b3s[128];
    const int t = threadIdx.x;
    const int b = blockIdx.x;

    // ---- weight staging (r19 original) ----
    for (int sid = t; sid < 64 * 32; sid += 512) {
        int k = sid >> 5, q = sid & 31;
        int jg = q >> 2, c = q & 3;
        W3v[(k << 5) + (c << 3) + jg] = ((const float4*)W3)[sid];
    }
    for (int cid = t; cid < 16 * 48; cid += 512) {
        int i = cid / 48, rem = cid - i * 48;
        int jq = rem >> 3, jg = rem & 7;
        int k = jg * 16 + i;
        float v0 = (4 * jq + 0 < 21) ? W4[k * 21 + 4 * jq + 0] : 0.f;
        float v1 = (4 * jq + 1 < 21) ? W4[k * 21 + 4 * jq + 1] : 0.f;
        float v2 = (4 * jq + 2 < 21) ? W4[k * 21 + 4 * jq + 2] : 0.f;
        float v3 = (4 * jq + 3 < 21) ? W4[k * 21 + 4 * jq + 3] : 0.f;
        W4v[cid] = make_float4(v0, v1, v2, v3);
    }
    if (t < 128) b3s[t] = b3[t];
    __syncthreads();

    // number of tiles this block owns (static assignment, r19)
    const int R = (TILES_TOTAL - b + PIPE_BLOCKS - 1) / PIPE_BLOCKS;

    for (int r = 0; r <= R; r++) {
        if (t < 256) {
            // ---- producer: gather tile r into xs[r&1] (fp16 h2) ----
            if (r < R) {
                const int l = t & 7;
                const int ny = t >> 3;
                const int node = (b + PIPE_BLOCKS * r) * 32 + ny;
                float4 acc0 = make_float4(0.f, 0.f, 0.f, 0.f);
                float4 acc1 = make_float4(0.f, 0.f, 0.f, 0.f);
                if (node < N) {
                    int s = rowptr[node], e = rowend[node];
                    float dn = dinv[node];
                    int i = s;
                    for (; i + 5 < e; i += 6) {
                        int r0 = csr_row[i],     r1 = csr_row[i + 1], r2 = csr_row[i + 2];
                        int r3 = csr_row[i + 3], r4 = csr_row[i + 4], r5 = csr_row[i + 5];
                        float w0 = dinv[r0] * dn, w1 = dinv[r1] * dn, w2 = dinv[r2] * dn;
                        float w3 = dinv[r3] * dn, w4 = dinv[r4] * dn, w5 = dinv[r5] * dn;
                        float4 v0 = h[(size_t)r0 * 8 + l];
                        float4 v1 = h[(size_t)r1 * 8 + l];
                        float4 v2 = h[(size_t)r2 * 8 + l];
                        float4 v3 = h[(size_t)r3 * 8 + l];
                        float4 v4 = h[(size_t)r4 * 8 + l];
                        float4 v5 = h[(size_t)r5 * 8 + l];
                        fma_h8(v0, w0, acc0, acc1);
                        fma_h8(v1, w1, acc0, acc1);
                        fma_h8(v2, w2, acc0, acc1);
                        fma_h8(v3, w3, acc0, acc1);
                        fma_h8(v4, w4, acc0, acc1);
                        fma_h8(v5, w5, acc0, acc1);
                    }
                    for (; i < e; i++) {
                        int r0 = csr_row[i];
                        float w0 = dinv[r0] * dn;
                        float4 v0 = h[(size_t)r0 * 8 + l];
                        fma_h8(v0, w0, acc0, acc1);
                    }
                }
                float* xr = xs[r & 1] + ny * 65 + 8 * l;
                xr[0] = acc0.x; xr[1] = acc0.y; xr[2] = acc0.z; xr[3] = acc0.w;
                xr[4] = acc1.x; xr[5] = acc1.y; xr[6] = acc1.z; xr[7] = acc1.w;
            }
        } else {
            // ---- consumer: GEMM tile r-1 from xs[(r-1)&1] (r25 structure) ----
            if (r >= 1) {
                const int jg = t & 7;
                const int ng = (t >> 3) & 31;
                const int node = (b + PIPE_BLOCKS * (r - 1)) * 32 + ng;
                const float* arow = xs[(r - 1) & 1] + ng * 65;

                float accA[16];
#pragma unroll
                for (int jj = 0; jj < 16; jj++) accA[jj] = 0.f;
#pragma unroll 4
                for (int k = 0; k < 64; k++) {
                    float xa = arow[k];
                    const float4* wb = &W3v[(k << 5) + jg];
#pragma unroll
                    for (int c = 0; c < 4; c++) {
                        float4 w = wb[c << 3];
                        accA[4 * c + 0] = fmaf(xa, w.x, accA[4 * c + 0]);
                        accA[4 * c + 1] = fmaf(xa, w.y, accA[4 * c + 1]);
                        accA[4 * c + 2] = fmaf(xa, w.z, accA[4 * c + 2]);
                        accA[4 * c + 3] = fmaf(xa, w.w, accA[4 * c + 3]);
                    }
                }
#pragma unroll
                for (int jj = 0; jj < 16; jj++) {
                    float bb = b3s[jg * 16 + jj];
                    accA[jj] = fmaxf(accA[jj] + bb, 0.f);
                }

                float pA[24];
#pragma unroll
                for (int j = 0; j < 24; j++) pA[j] = 0.f;
#pragma unroll
                for (int i = 0; i < 16; i++) {
                    float ha = accA[i];
                    const float4* wb = &W4v[i * 48 + jg];
#pragma unroll
                    for (int jq = 0; jq < 6; jq++) {
                        float4 w = wb[jq << 3];
                        pA[4 * jq + 0] = fmaf(ha, w.x, pA[4 * jq + 0]);
                        pA[4 * jq + 1] = fmaf(ha, w.y, pA[4 * jq + 1]);
                        pA[4 * jq + 2] = fmaf(ha, w.z, pA[4 * jq + 2]);
                        pA[4 * jq + 3] = fmaf(ha, w.w, pA[4 * jq + 3]);
                    }
                }
#pragma unroll
                for (int m = 1; m < 8; m <<= 1) {
#pragma unroll
                    for (int j = 0; j < 24; j++)
                        pA[j] += __shfl_xor(pA[j], m, 8);
                }
                if (node < N) {
                    __half* orow = (__half*)out + (size_t)node * 32;
                    float2 pk = make_float2(0.f, 0.f);   // 4 zero halfs
                    if (jg < 6) {
                        __half2* ph = (__half2*)&pk;
                        ph[0] = __float22half2_rn(make_float2(pA[4 * jg + 0], pA[4 * jg + 1]));
                        ph[1] = __float22half2_rn(make_float2(pA[4 * jg + 2], pA[4 * jg + 3]));
                    }
                    *(float2*)(orow + 4 * jg) = pk;
                }
            }
        }
        __syncthreads();
    }
}

// ======================= launch ==========================================
extern "C" void kernel_launch(void* const* d_in, const int* in_sizes, int n_in,
                              void* d_out, int out_size, void* d_ws, size_t ws_size,
                              hipStream_t stream) {
    const float* x  = (const float*)d_in[0];
    const int*   ei = (const int*)d_in[1];
    const float* W1 = (const float*)d_in[2]; const float* b1 = (const float*)d_in[3];
    const float* W2 = (const float*)d_in[4]; const float* b2 = (const float*)d_in[5];
    const float* W3 = (const float*)d_in[6]; const float* b3 = (const float*)d_in[7];
    const float* W4 = (const float*)d_in[8]; const float* b4 = (const float*)d_in[9];
    const int* row = ei;
    const int* col = ei + NE;
    float* out = (float*)d_out;

    // workspace layout (floats)
    float* A      = (float*)d_ws;                  // region A: packed -> h1(fp16) -> h4(fp16)
    float* B      = A + (size_t)NN * 128;          // region B: y1(fp16) -> h2(fp16)
    float* dinv   = B + (size_t)NN * 128;          // N
    int*   rowptr = (int*)(dinv + NN);             // N
    int*   rowend = rowptr + NN;                   // N
    int*   csr_row= rowend + NN;                   // NB_BKT * CSRCAP = 2.5M
    int*   bcur   = csr_row + (size_t)NB_BKT * CSRCAP;   // NB_BKT
    // packed u32 (r<<7 | c&127), bucket-strided cap BCAP; aliases A (dead pre-L1)
    unsigned int* packed = (unsigned int*)A;       // NB_BKT * BCAP = 2.4M < N*128

    const int NCH = cdiv(NE, CHUNK);    // 391

    // ---- y1 = x @ W1 (fp16) + bcur init ----
    xw1_kernel<<<cdiv(NN, 64), 256, 0, stream>>>(x, W1, (__half*)B, bcur, NN);
    // ---- fixed-cap bucketed CSR build (2 dispatches) ----
    partition_kernel<<<NCH, 256, 0, stream>>>(row, col, bcur, packed, NE);
    bucket_nodes_place<<<NB_BKT, 256, 0, stream>>>(packed, bcur, rowptr, rowend, dinv, csr_row, NN);

    // ---- L1: gather(y1 fp16) + b1 + relu : B -> A (h1 FP16, 64B rows) ----
    {
        dim3 blk(8, 32);
        gather4_kernel<8, true, false, true, true><<<cdiv(NN, 32), blk, 0, stream>>>(
            (const float4*)B, rowptr, rowend, csr_row, dinv, b1, A, NN);
    }
    // ---- L2: gather(h1 fp16)+gemm 32->64 +b relu : A -> B (h2 FP16, 128B rows) ----
    gather_gemm<8, 32, 64, 8, 64, true, true><<<cdiv(NN, 64), 512, 0, stream>>>(
        (const float4*)A, rowptr, rowend, csr_row, dinv, W2, b2, B, NN);
    // ---- pipelined fused L3 gather(fp16 h2) + L3/L4 GEMM: B -> A (h4 FP16, 64B rows) --
    gather_gemm_l3l4_pipe<<<PIPE_BLOCKS, 512, 0, stream>>>(
        (const float4*)B, rowptr, rowend, csr_row, dinv, W3, b3, W4, A, NN);
    // ---- L4 gather(h4 fp16) + b4: A -> out (f32, stride 21) ----
    {
        dim3 blk(8, 32);
        gather4_kernel<8, true, true, true, false><<<cdiv(NN, 32), blk, 0, stream>>>(
            (const float4*)A, rowptr, rowend, csr_row, dinv, b4, out, NN);
    }
}